// Round 10
// baseline (72.892 us; speedup 1.0000x reference)
//
#include <hip/hip_runtime.h>
#include <math.h>

// ---------------------------------------------------------------------------
// B=32768 segments, E=1M sorted edges, DIM=64.
//   score[e] = dot(H[h[s]], R[rel[e]])
//   w        = segment_softmax(score)      (no-max: |dot|<~40, f32 exp exact
//                                           cancellation of max in ratio)
//   c_e      = sum_d T[tail_e] - sum_d R[rel_e]
//   out[s][:]= broadcast((sum w*c))
//
// SINGLE ordinary launch, zero inter-block dependencies (R3/R5/R6 showed
// grid-sync is pathological on 8-XCD; R2..R9 showed the 2-dispatch pipeline
// is pinned at ~23us regardless of kernel internals -> boundary overhead).
// Every block (32 segments) is self-sufficient:
//   - Rt (R transposed) + rsum in LDS            (15 KB L2 reads/block)
//   - its 32 P-rows recomputed in LDS            (123K FMA/block, ~1.6us chip)
//   - segment bounds via 33-lane binary search
//   - per-edge c via coalesced T-row prepass into c_lds (16 lanes/row,
//     2 cachelines/row, L2-resident T) -- replaces the tsum table kernel.
// ---------------------------------------------------------------------------

#define RT_S 61        // padded LDS stride for Rt[d][r]: gcd(61,32)=1 -> 2-way max
#define CAP  2048      // staged-edge cap per block (avg 1024, sigma~32, +32sigma)

__global__ __launch_bounds__(256) void fused_k(
    const int* __restrict__ h, const int* __restrict__ eseg,
    const int* __restrict__ erel, const int* __restrict__ etail,
    const float* __restrict__ H, const float* __restrict__ R,
    const float* __restrict__ T, float* __restrict__ out,
    int B, int E, int NR)
{
    __shared__ float Rt[64 * RT_S];     // 15.6 KB
    __shared__ float P_lds[2048];       // 32*NR <= 2048 (8 KB)
    __shared__ float c_lds[CAP];        // 8 KB
    __shared__ float rs[64];
    __shared__ int   bounds[33];
    __shared__ int   h_lds[32];

    const int tid  = threadIdx.x;
    const int base = blockIdx.x * 32;

    // ---- A0: head ids + stage R transposed ----
    if (tid < 32 && base + tid < B) h_lds[tid] = h[base + tid];
    for (int t = tid; t < NR * 64; t += 256) {
        int r = t >> 6, d = t & 63;
        Rt[d * RT_S + r] = R[t];        // write banks: (61d+r)%32, 2-way max
    }
    __syncthreads();

    // ---- A1 static split: 33 lanes search bounds | 223 build P/rsum ----
    if (tid >= 223) {
        int s = base + tid - 223;       // target segment id (<= base+32)
        int lo = 0, hi = E;
        while (lo < hi) {               // lower_bound(eseg, s), ~20 L2 probes
            int mid = (lo + hi) >> 1;
            if (eseg[mid] < s) lo = mid + 1; else hi = mid;
        }
        bounds[tid - 223] = lo;
    } else {
        if (tid < NR) {
            float s = 0.f;
            for (int d = 0; d < 64; ++d) s += Rt[d * RT_S + tid];
            rs[tid] = s;
        }
        const int tot = 32 * NR;        // 1920 exp-dots for this block's heads
        for (int t = tid; t < tot; t += 223) {
            int j = t / NR, r = t - j * NR;
            const float4* h4 = (const float4*)(H + (size_t)h_lds[j] * 64);
            float acc = 0.f;
            #pragma unroll
            for (int q = 0; q < 16; ++q) {
                float4 hv = h4[q];      // same row across ~60 threads: L1 hit
                int d = q * 4;
                acc = fmaf(hv.x, Rt[(d + 0) * RT_S + r], acc);
                acc = fmaf(hv.y, Rt[(d + 1) * RT_S + r], acc);
                acc = fmaf(hv.z, Rt[(d + 2) * RT_S + r], acc);
                acc = fmaf(hv.w, Rt[(d + 3) * RT_S + r], acc);
            }
            P_lds[t] = __expf(acc);
        }
    }
    __syncthreads();

    const int eLo = bounds[0];
    const int eHi = bounds[32];

    // ---- A2: prepass -- c_lds[e-eLo] = sum_d T[tail_e]  (coalesced rows:
    //      16 lanes x float4 = one 256B row = 2 cachelines; 4 rows/wave/iter)
    {
        int wave = tid >> 6, lane = tid & 63;
        int g = lane >> 4, l16 = lane & 15;
        int nCap = min(eHi, eLo + CAP);
        for (int e4 = eLo + wave * 4; e4 < nCap; e4 += 16) {
            int e = e4 + g;
            float s = 0.f;
            if (e < nCap) {
                int tl = etail[e];      // 16 lanes same addr: broadcast
                float4 v = ((const float4*)T)[(size_t)tl * 16 + l16];
                s = v.x + v.y + v.z + v.w;
            }
            s += __shfl_xor(s, 8, 64);
            s += __shfl_xor(s, 4, 64);
            s += __shfl_xor(s, 2, 64);
            s += __shfl_xor(s, 1, 64);
            if (l16 == 0 && e < nCap) c_lds[e - eLo] = s;
        }
    }
    __syncthreads();

    // ---- B: 8 groups of 32 lanes x 4 iterations = 32 segments ----
    int sub = tid & 31, gidx = tid >> 5;
    #pragma unroll
    for (int k = 0; k < 4; ++k) {
        int j   = gidx + k * 8;
        int grp = base + j;
        if (grp >= B) break;
        int lo = bounds[j], hi = bounds[j + 1];
        const float* Pj = P_lds + j * NR;

        float se = 0.f, sec = 0.f;
        for (int e = lo + sub; e < hi; e += 32) {
            int rel  = erel[e];
            float pv = Pj[rel];
            float c;
            int ci = e - eLo;
            if (ci < CAP) c = c_lds[ci];
            else {                       // overflow fallback (statistically never)
                const float4* t4 = (const float4*)(T + (size_t)etail[e] * 64);
                float4 a = t4[0];
                #pragma unroll
                for (int q = 1; q < 16; ++q) {
                    float4 v = t4[q];
                    a.x += v.x; a.y += v.y; a.z += v.z; a.w += v.w;
                }
                c = a.x + a.y + a.z + a.w;
            }
            c -= rs[rel];
            sec = fmaf(pv, c, sec);
            se += pv;
        }
        #pragma unroll
        for (int off = 16; off; off >>= 1) {
            se  += __shfl_xor(se, off, 64);
            sec += __shfl_xor(sec, off, 64);
        }
        float vc = (se > 0.f) ? (sec / se) : 0.f;
        *(float2*)(out + (size_t)grp * 64 + sub * 2) = make_float2(vc, vc);
    }
}

extern "C" void kernel_launch(void* const* d_in, const int* in_sizes, int n_in,
                              void* d_out, int out_size, void* d_ws, size_t ws_size,
                              hipStream_t stream)
{
    const int*   h     = (const int*)d_in[0];
    const int*   eseg  = (const int*)d_in[1];
    const int*   erel  = (const int*)d_in[2];
    const int*   etail = (const int*)d_in[3];
    const float* Hv    = (const float*)d_in[4];
    const float* Rv    = (const float*)d_in[5];
    const float* Tv    = (const float*)d_in[6];

    int B  = in_sizes[0];
    int E  = in_sizes[1];
    int NR = in_sizes[5] / 64;
    (void)d_ws; (void)ws_size; (void)n_in; (void)out_size;

    fused_k<<<(B + 31) / 32, 256, 0, stream>>>(
        h, eseg, erel, etail, Hv, Rv, Tv, (float*)d_out, B, E, NR);
}